// Round 3
// baseline (2064.861 us; speedup 1.0000x reference)
//
#include <hip/hip_runtime.h>

// MAF forward: 32 autoregressive MADE steps, fully fused.
// N=65536 samples, D=32, H=1024, C=64.
// ws layout (bf16 as u16):
//   [0      .. 32768)  W1mT [h=1024][d=32]   = W1[d][h]*mask1
//   [32768  .. 98304)  W2mT [c=64][h=1024]   = W2[h][c]*mask2   (c = d*2+p)
//   [98304  ..163840)  WcT  [h=1024][c=64]   = Wc[c][h]

#define NS 65536
#define HH 1024

typedef __attribute__((ext_vector_type(8))) short short8;
typedef __attribute__((ext_vector_type(4))) float f32x4;

__device__ inline unsigned short f2bf(float f) {
  unsigned int u = __builtin_bit_cast(unsigned int, f);
  u += 0x7fffu + ((u >> 16) & 1u);          // RNE
  return (unsigned short)(u >> 16);
}
__device__ inline unsigned int pack2bf(float a, float b) {
  return (unsigned int)f2bf(a) | ((unsigned int)f2bf(b) << 16);
}
__device__ inline float bflo(unsigned int p) { return __builtin_bit_cast(float, p << 16); }
__device__ inline float bfhi(unsigned int p) { return __builtin_bit_cast(float, p & 0xffff0000u); }
// tanh(x) = 1 - 2/(1+e^{2x}); saturates correctly for |x| large
__device__ inline float tanh_fast(float x) {
  float t = __expf(2.0f * x);
  float r = __builtin_amdgcn_rcpf(t + 1.0f);
  return fmaf(-2.0f, r, 1.0f);
}

__global__ void maf_prep(const float* __restrict__ W1, const float* __restrict__ Wc,
                         const float* __restrict__ W2, unsigned short* __restrict__ ws) {
  int t = blockIdx.x * blockDim.x + threadIdx.x;     // 0 .. 163839
  if (t < 32768) {                                   // W1mT [h][d]
    int h = t >> 5, d = t & 31;
    int deg = h % 31 + 1;                            // hid_deg
    float v = (deg >= d + 1) ? W1[(size_t)d * HH + h] : 0.f;
    ws[t] = f2bf(v);
  } else if (t < 98304) {                            // W2mT [c][h]
    int i = t - 32768;
    int c = i >> 10, h = i & 1023;
    int deg = h % 31 + 1;
    float v = (((c >> 1) + 1) > deg) ? W2[(size_t)h * 64 + c] : 0.f;
    ws[t] = f2bf(v);
  } else {                                           // WcT [h][c]
    int i = t - 98304;
    int h = i >> 6, c = i & 63;
    ws[t] = f2bf(Wc[(size_t)c * HH + h]);
  }
}

__global__ __launch_bounds__(512, 4) void maf_main(
    const float* __restrict__ x, const float* __restrict__ ctx,
    const float* __restrict__ b1, const float* __restrict__ b2,
    const unsigned short* __restrict__ ws, float* __restrict__ out)
{
  // LDS: 66048 + 2560 + 512 = 69120 B -> 2 blocks/CU
  __shared__ __align__(16) unsigned short hidb[32][1032];  // hid bf16 [s][h], pitch 2064B
  __shared__ __align__(16) unsigned short ybf[32][40];     // y bf16 [s][d]
  __shared__ float ldp[2][16][4];                          // log_det partials [st][s][ct]

  const unsigned short* W1mT = ws;            // [1024][32]
  const unsigned short* W2mT = ws + 32768;    // [64][1024]
  const unsigned short* WcT  = ws + 98304;    // [1024][64]

  const int tid  = threadIdx.x;
  const int lane = tid & 63;
  const int w    = tid >> 6;        // wave 0..7
  const int l15  = lane & 15;
  const int lk   = lane >> 4;       // 0..3
  const int s0   = blockIdx.x * 32;

  // zero y
  for (int i = tid; i < 640; i += 512)
    reinterpret_cast<unsigned int*>(&ybf[0][0])[i] = 0u;

  // ---- ctx B-fragments straight from global (f32 -> bf16 RNE pack) ----
  short8 cf[2][2];
#pragma unroll
  for (int sh = 0; sh < 2; ++sh)
#pragma unroll
    for (int kc = 0; kc < 2; ++kc) {
      const float* cp = ctx + (size_t)(s0 + sh * 16 + l15) * 64 + kc * 32 + lk * 8;
      f32x4 a = *reinterpret_cast<const f32x4*>(cp);
      f32x4 b = *reinterpret_cast<const f32x4*>(cp + 4);
      union { short8 s; unsigned int u[4]; } t;
      t.u[0] = pack2bf(a[0], a[1]);
      t.u[1] = pack2bf(a[2], a[3]);
      t.u[2] = pack2bf(b[0], b[1]);
      t.u[3] = pack2bf(b[2], b[3]);
      cf[sh][kc] = t.s;
    }

  // ---- WcH^T + b1: rows h = h0+4lk+r, col s = l15; packed bf16 in regs (32 u32) ----
  unsigned int wchp[2][8][2];
#pragma unroll
  for (int j = 0; j < 8; ++j) {
    int h0 = (w * 8 + j) * 16;
    f32x4 binit = *reinterpret_cast<const f32x4*>(b1 + h0 + 4 * lk);
#pragma unroll
    for (int sh = 0; sh < 2; ++sh) {
      f32x4 acc = binit;
#pragma unroll
      for (int kc = 0; kc < 2; ++kc) {
        short8 af = *reinterpret_cast<const short8*>(WcT + (size_t)(h0 + l15) * 64 + kc * 32 + lk * 8);
        acc = __builtin_amdgcn_mfma_f32_16x16x32_bf16(af, cf[sh][kc], acc, 0, 0, 0);
      }
      wchp[sh][j][0] = pack2bf(acc[0], acc[1]);
      wchp[sh][j][1] = pack2bf(acc[2], acc[3]);
    }
  }

  // ---- GEMM2 / epilogue roles ----
  const int st = w >> 2, ct = w & 3;           // sample tile, col tile
  const int c  = 16 * ct + l15;                // output column c = 2d+p
  const int d  = c >> 1;
  const bool evn = ((lane & 1) == 0);
  float xr[4];
#pragma unroll
  for (int r = 0; r < 4; ++r)
    xr[r] = x[(size_t)(s0 + 16 * st + 4 * lk + r) * 32 + d];
  const float b2e = b2[2 * d], b2o = b2[2 * d + 1];
  float lsr[4] = {0.f, 0.f, 0.f, 0.f};
  const unsigned short* w1base = W1mT + (size_t)(w * 128 + l15) * 32 + lk * 8;  // +j*512 per j
  const unsigned short* wrow   = W2mT + (size_t)c * 1024 + lk * 8;
  const unsigned short* hrow0  = &hidb[16 * st + l15][lk * 8];

  __syncthreads();

  for (int step = 0; step < 32; ++step) {
    // anti-LICM: force W1/W2 loads to stay inside the loop (reloads are L1/L2
    // hits; hoisting 8-32 b128 loads into regs re-creates the R1 spill)
    const unsigned short* w1p = w1base;
    const unsigned short* w2p = wrow;
    asm volatile("" : "+v"(w1p), "+v"(w2p));

    // ---- GEMM1: hidT[h][s] = W1m^T @ y^T (+WcH); lane gets 4 contig h per sample ----
    short8 yb0 = *reinterpret_cast<const short8*>(&ybf[l15][lk * 8]);
    short8 yb1 = *reinterpret_cast<const short8*>(&ybf[16 + l15][lk * 8]);
#pragma unroll
    for (int j = 0; j < 8; ++j) {
      short8 w1f = *reinterpret_cast<const short8*>(w1p + (size_t)j * 512);
      unsigned int pk0 = wchp[0][j][0], pk1 = wchp[0][j][1];
      f32x4 c0 = {bflo(pk0), bfhi(pk0), bflo(pk1), bfhi(pk1)};
      c0 = __builtin_amdgcn_mfma_f32_16x16x32_bf16(w1f, yb0, c0, 0, 0, 0);
      unsigned int qk0 = wchp[1][j][0], qk1 = wchp[1][j][1];
      f32x4 c1 = {bflo(qk0), bfhi(qk0), bflo(qk1), bfhi(qk1)};
      c1 = __builtin_amdgcn_mfma_f32_16x16x32_bf16(w1f, yb1, c1, 0, 0, 0);
      int h0 = (w * 8 + j) * 16;
      uint2 q0, q1;
      q0.x = pack2bf(tanh_fast(c0[0]), tanh_fast(c0[1]));
      q0.y = pack2bf(tanh_fast(c0[2]), tanh_fast(c0[3]));
      q1.x = pack2bf(tanh_fast(c1[0]), tanh_fast(c1[1]));
      q1.y = pack2bf(tanh_fast(c1[2]), tanh_fast(c1[3]));
      *reinterpret_cast<uint2*>(&hidb[l15][h0 + 4 * lk]) = q0;       // sample l15
      *reinterpret_cast<uint2*>(&hidb[16 + l15][h0 + 4 * lk]) = q1;  // sample 16+l15
    }
    __syncthreads();

    // ---- GEMM2: P[s][c] = hid @ W2m, full K=1024 per wave, 2 accumulator chains ----
    f32x4 pa = {0.f, 0.f, 0.f, 0.f}, pb = {0.f, 0.f, 0.f, 0.f};
#pragma unroll 2
    for (int ks = 0; ks < 32; ks += 2) {
      short8 a0  = *reinterpret_cast<const short8*>(hrow0 + ks * 32);
      short8 wb0 = *reinterpret_cast<const short8*>(w2p + ks * 32);
      pa = __builtin_amdgcn_mfma_f32_16x16x32_bf16(a0, wb0, pa, 0, 0, 0);
      short8 a1  = *reinterpret_cast<const short8*>(hrow0 + ks * 32 + 32);
      short8 wb1 = *reinterpret_cast<const short8*>(w2p + ks * 32 + 32);
      pb = __builtin_amdgcn_mfma_f32_16x16x32_bf16(a1, wb1, pb, 0, 0, 0);
    }
    f32x4 p = pa + pb;   // lane: P[16st+4lk+r][c]

    // ---- epilogue in-register: pair-exchange shift/log_scale via shfl ----
    const bool last = (step == 31);
#pragma unroll
    for (int r = 0; r < 4; ++r) {
      float q = __shfl_xor(p[r], 1);        // partner column c^1 (both lanes execute)
      if (evn) {
        float shv = p[r] + b2e;             // even c = 2d -> shift
        float lsv = q + b2o;                // odd  c = 2d+1 -> log_scale
        float yv = fmaf(xr[r], __expf(lsv), shv);
        ybf[16 * st + 4 * lk + r][d] = f2bf(yv);
        if (last) {
          lsr[r] = lsv;
          out[(size_t)(s0 + 16 * st + 4 * lk + r) * 32 + d] = yv;
        }
      }
    }
    __syncthreads();
  }

  // ---- log_det: sum last-step log_scale over d ----
#pragma unroll
  for (int r = 0; r < 4; ++r) {
    float v = lsr[r];                       // non-contributing lanes carry 0
    v += __shfl_xor(v, 2);
    v += __shfl_xor(v, 4);
    v += __shfl_xor(v, 8);
    if (l15 == 0) ldp[st][4 * lk + r][ct] = v;
  }
  __syncthreads();
  if (tid < 32) {
    const float* lp = &ldp[tid >> 4][tid & 15][0];
    out[(size_t)NS * 32 + s0 + tid] = lp[0] + lp[1] + lp[2] + lp[3];
  }
}

extern "C" void kernel_launch(void* const* d_in, const int* in_sizes, int n_in,
                              void* d_out, int out_size, void* d_ws, size_t ws_size,
                              hipStream_t stream) {
  (void)in_sizes; (void)n_in; (void)out_size; (void)ws_size;
  const float* x   = (const float*)d_in[0];
  const float* ctx = (const float*)d_in[1];
  const float* W1  = (const float*)d_in[2];
  const float* b1  = (const float*)d_in[3];
  const float* Wc  = (const float*)d_in[4];
  const float* W2  = (const float*)d_in[5];
  const float* b2  = (const float*)d_in[6];
  unsigned short* ws = (unsigned short*)d_ws;
  float* out = (float*)d_out;

  maf_prep<<<640, 256, 0, stream>>>(W1, Wc, W2, ws);
  maf_main<<<2048, 512, 0, stream>>>(x, ctx, b1, b2, ws, out);
}

// Round 4
// 1077.019 us; speedup vs baseline: 1.9172x; 1.9172x over previous
//
#include <hip/hip_runtime.h>

// MAF forward: 32 autoregressive MADE steps, fully fused.
// N=65536, D=32, H=1024, C=64.
// R3: 1024-thread blocks (16 waves, 1 block/CU). All weights register-resident:
//   W1 frags 16 VGPR/wave, W2 frags 32 VGPR/wave (c-tile x K-quarter split),
//   WcH+b1 packed bf16 16 VGPR/wave. Step loop touches only LDS/registers.
// ws layout (bf16 as u16):
//   [0      .. 32768)  W1mT [h=1024][d=32]   = W1[d][h]*mask1
//   [32768  .. 98304)  W2mT [c=64][h=1024]   = W2[h][c]*mask2   (c = d*2+p)
//   [98304  ..163840)  WcT  [h=1024][c=64]   = Wc[c][h]

#define NS 65536
#define HH 1024

typedef __attribute__((ext_vector_type(8))) short short8;
typedef __attribute__((ext_vector_type(4))) float f32x4;

__device__ inline unsigned short f2bf(float f) {
  unsigned int u = __builtin_bit_cast(unsigned int, f);
  u += 0x7fffu + ((u >> 16) & 1u);          // RNE
  return (unsigned short)(u >> 16);
}
__device__ inline unsigned int pack2bf(float a, float b) {
  return (unsigned int)f2bf(a) | ((unsigned int)f2bf(b) << 16);
}
__device__ inline float bflo(unsigned int p) { return __builtin_bit_cast(float, p << 16); }
__device__ inline float bfhi(unsigned int p) { return __builtin_bit_cast(float, p & 0xffff0000u); }
// tanh(x) = 1 - 2/(1+e^{2x}); saturates correctly for |x| large
__device__ inline float tanh_fast(float x) {
  float t = __expf(2.0f * x);
  float r = __builtin_amdgcn_rcpf(t + 1.0f);
  return fmaf(-2.0f, r, 1.0f);
}

__global__ void maf_prep(const float* __restrict__ W1, const float* __restrict__ Wc,
                         const float* __restrict__ W2, unsigned short* __restrict__ ws) {
  int t = blockIdx.x * blockDim.x + threadIdx.x;     // 0 .. 163839
  if (t < 32768) {                                   // W1mT [h][d]
    int h = t >> 5, d = t & 31;
    int deg = h % 31 + 1;                            // hid_deg
    float v = (deg >= d + 1) ? W1[(size_t)d * HH + h] : 0.f;
    ws[t] = f2bf(v);
  } else if (t < 98304) {                            // W2mT [c][h]
    int i = t - 32768;
    int c = i >> 10, h = i & 1023;
    int deg = h % 31 + 1;
    float v = (((c >> 1) + 1) > deg) ? W2[(size_t)h * 64 + c] : 0.f;
    ws[t] = f2bf(v);
  } else {                                           // WcT [h][c]
    int i = t - 98304;
    int h = i >> 6, c = i & 63;
    ws[t] = f2bf(Wc[(size_t)c * HH + h]);
  }
}

__global__ __launch_bounds__(1024, 4) void maf_main(
    const float* __restrict__ x, const float* __restrict__ ctx,
    const float* __restrict__ b1, const float* __restrict__ b2,
    const unsigned short* __restrict__ ws, float* __restrict__ out)
{
  // LDS: 66048 + 2560 + 34816 = 103424 B -> 1 block/CU (4 waves/SIMD)
  __shared__ __align__(16) unsigned short hidb[32][1032];  // hid bf16 [s][h]
  __shared__ __align__(16) unsigned short ybf[32][40];     // y bf16 [s][d]
  __shared__ __align__(16) float Pp4[4][32][68];           // GEMM2 K-quarter partials

  const unsigned short* W1mT = ws;            // [1024][32]
  const unsigned short* W2mT = ws + 32768;    // [64][1024]
  const unsigned short* WcT  = ws + 98304;    // [1024][64]

  const int tid  = threadIdx.x;
  const int lane = tid & 63;
  const int w    = tid >> 6;        // wave 0..15
  const int l15  = lane & 15;
  const int lk   = lane >> 4;       // 0..3
  const int s0   = blockIdx.x * 32;

  // zero y
  if (tid < 640) reinterpret_cast<unsigned int*>(&ybf[0][0])[tid] = 0u;

  // ---- ctx B-fragments from global (f32 -> bf16 RNE) ----
  short8 cf[2][2];
#pragma unroll
  for (int sh = 0; sh < 2; ++sh)
#pragma unroll
    for (int kc = 0; kc < 2; ++kc) {
      const float* cp = ctx + (size_t)(s0 + sh * 16 + l15) * 64 + kc * 32 + lk * 8;
      f32x4 a = *reinterpret_cast<const f32x4*>(cp);
      f32x4 b = *reinterpret_cast<const f32x4*>(cp + 4);
      union { short8 s; unsigned int u[4]; } t;
      t.u[0] = pack2bf(a[0], a[1]);
      t.u[1] = pack2bf(a[2], a[3]);
      t.u[2] = pack2bf(b[0], b[1]);
      t.u[3] = pack2bf(b[2], b[3]);
      cf[sh][kc] = t.s;
    }

  // ---- WcH^T + b1 for this wave's 64 h-rows; packed bf16 (16 regs) ----
  unsigned int wchp[2][4][2];
#pragma unroll
  for (int j = 0; j < 4; ++j) {
    int h0 = w * 64 + j * 16;
    f32x4 binit = *reinterpret_cast<const f32x4*>(b1 + h0 + 4 * lk);
#pragma unroll
    for (int sh = 0; sh < 2; ++sh) {
      f32x4 acc = binit;
#pragma unroll
      for (int kc = 0; kc < 2; ++kc) {
        short8 af = *reinterpret_cast<const short8*>(WcT + (size_t)(h0 + l15) * 64 + kc * 32 + lk * 8);
        acc = __builtin_amdgcn_mfma_f32_16x16x32_bf16(af, cf[sh][kc], acc, 0, 0, 0);
      }
      wchp[sh][j][0] = pack2bf(acc[0], acc[1]);
      wchp[sh][j][1] = pack2bf(acc[2], acc[3]);
    }
  }

  // ---- W1 A-fragments, register-resident (16 regs) ----
  short8 w1f[4];
#pragma unroll
  for (int j = 0; j < 4; ++j)
    w1f[j] = *reinterpret_cast<const short8*>(W1mT + (size_t)(w * 64 + j * 16 + l15) * 32 + lk * 8);

  // ---- W2 B-fragments, register-resident (32 regs); wave = (ct, kq) ----
  const int ct = w & 3, kq = w >> 2;
  short8 w2f[8];
#pragma unroll
  for (int ks = 0; ks < 8; ++ks)
    w2f[ks] = *reinterpret_cast<const short8*>(
        W2mT + (size_t)(16 * ct + l15) * 1024 + kq * 256 + ks * 32 + lk * 8);

  // ---- epilogue role: thread -> (sample se, dim de) ----
  const int se = tid >> 5, de = tid & 31;
  const float xv  = x[(size_t)(s0 + se) * 32 + de];
  const float b2e = b2[2 * de], b2o = b2[2 * de + 1];
  float ls_last = 0.f;

  __syncthreads();

#pragma unroll 1
  for (int step = 0; step < 32; ++step) {
    // ---- GEMM1: hidT[h][s] = W1m^T @ y^T (+WcH); 4 h-subtiles per wave ----
    short8 yb0 = *reinterpret_cast<const short8*>(&ybf[l15][lk * 8]);
    short8 yb1 = *reinterpret_cast<const short8*>(&ybf[16 + l15][lk * 8]);
#pragma unroll
    for (int j = 0; j < 4; ++j) {
      unsigned int pk0 = wchp[0][j][0], pk1 = wchp[0][j][1];
      f32x4 c0 = {bflo(pk0), bfhi(pk0), bflo(pk1), bfhi(pk1)};
      c0 = __builtin_amdgcn_mfma_f32_16x16x32_bf16(w1f[j], yb0, c0, 0, 0, 0);
      unsigned int qk0 = wchp[1][j][0], qk1 = wchp[1][j][1];
      f32x4 c1 = {bflo(qk0), bfhi(qk0), bflo(qk1), bfhi(qk1)};
      c1 = __builtin_amdgcn_mfma_f32_16x16x32_bf16(w1f[j], yb1, c1, 0, 0, 0);
      int h0 = w * 64 + j * 16;
      uint2 q0, q1;
      q0.x = pack2bf(tanh_fast(c0[0]), tanh_fast(c0[1]));
      q0.y = pack2bf(tanh_fast(c0[2]), tanh_fast(c0[3]));
      q1.x = pack2bf(tanh_fast(c1[0]), tanh_fast(c1[1]));
      q1.y = pack2bf(tanh_fast(c1[2]), tanh_fast(c1[3]));
      *reinterpret_cast<uint2*>(&hidb[l15][h0 + 4 * lk]) = q0;       // sample l15
      *reinterpret_cast<uint2*>(&hidb[16 + l15][h0 + 4 * lk]) = q1;  // sample 16+l15
    }
    __syncthreads();

    // ---- GEMM2: P[s][c] partial over this wave's K-quarter; W2 from regs ----
    {
      const unsigned short* ha0 = &hidb[l15][kq * 256 + lk * 8];
      const unsigned short* ha1 = &hidb[16 + l15][kq * 256 + lk * 8];
      f32x4 p0 = {0.f, 0.f, 0.f, 0.f}, p1 = {0.f, 0.f, 0.f, 0.f};
#pragma unroll
      for (int ks = 0; ks < 8; ++ks) {
        short8 a0 = *reinterpret_cast<const short8*>(ha0 + ks * 32);
        p0 = __builtin_amdgcn_mfma_f32_16x16x32_bf16(a0, w2f[ks], p0, 0, 0, 0);
        short8 a1 = *reinterpret_cast<const short8*>(ha1 + ks * 32);
        p1 = __builtin_amdgcn_mfma_f32_16x16x32_bf16(a1, w2f[ks], p1, 0, 0, 0);
      }
#pragma unroll
      for (int r = 0; r < 4; ++r) {
        Pp4[kq][4 * lk + r][16 * ct + l15]      = p0[r];
        Pp4[kq][16 + 4 * lk + r][16 * ct + l15] = p1[r];
      }
    }
    __syncthreads();

    // ---- epilogue: thread (se, de): sum K-quarters, y = x*exp(ls) + sh ----
    {
      float sh = b2e, ls = b2o;
#pragma unroll
      for (int q = 0; q < 4; ++q) {
        float2 v = *reinterpret_cast<const float2*>(&Pp4[q][se][2 * de]);
        sh += v.x; ls += v.y;
      }
      float yv = fmaf(xv, __expf(ls), sh);
      ybf[se][de] = f2bf(yv);
      if (step == 31) {
        out[(size_t)(s0 + se) * 32 + de] = yv;
        ls_last = ls;
      }
    }
    __syncthreads();
  }

  // ---- log_det: reduce ls over de within each 32-lane group ----
  float v = ls_last;
  v += __shfl_xor(v, 1);
  v += __shfl_xor(v, 2);
  v += __shfl_xor(v, 4);
  v += __shfl_xor(v, 8);
  v += __shfl_xor(v, 16);
  if (de == 0) out[(size_t)NS * 32 + s0 + se] = v;
}

extern "C" void kernel_launch(void* const* d_in, const int* in_sizes, int n_in,
                              void* d_out, int out_size, void* d_ws, size_t ws_size,
                              hipStream_t stream) {
  (void)in_sizes; (void)n_in; (void)out_size; (void)ws_size;
  const float* x   = (const float*)d_in[0];
  const float* ctx = (const float*)d_in[1];
  const float* W1  = (const float*)d_in[2];
  const float* b1  = (const float*)d_in[3];
  const float* Wc  = (const float*)d_in[4];
  const float* W2  = (const float*)d_in[5];
  const float* b2  = (const float*)d_in[6];
  unsigned short* ws = (unsigned short*)d_ws;
  float* out = (float*)d_out;

  maf_prep<<<640, 256, 0, stream>>>(W1, Wc, W2, ws);
  maf_main<<<2048, 1024, 0, stream>>>(x, ctx, b1, b2, ws, out);
}

// Round 5
// 925.408 us; speedup vs baseline: 2.2313x; 1.1638x over previous
//
#include <hip/hip_runtime.h>

// MAF forward: 32 autoregressive MADE steps, fully fused.
// N=65536, D=32, H=1024, C=64.
// R4 = R3 (16 waves, weights register-resident, 1 block/CU) + VALU diet:
//   v_cvt_pk_bf16_f32 packing, f32 WcH accumulators, exp2-folded tanh.
// ws layout (bf16 as u16):
//   [0      .. 32768)  W1mT [h=1024][d=32]   = W1[d][h]*mask1
//   [32768  .. 98304)  W2mT [c=64][h=1024]   = W2[h][c]*mask2   (c = d*2+p)
//   [98304  ..163840)  WcT  [h=1024][c=64]   = Wc[c][h]

#define NS 65536
#define HH 1024

typedef __attribute__((ext_vector_type(8))) short short8;
typedef __attribute__((ext_vector_type(4))) float f32x4;

__device__ inline unsigned short f2bf(float f) {
  unsigned int u = __builtin_bit_cast(unsigned int, f);
  u += 0x7fffu + ((u >> 16) & 1u);          // RNE
  return (unsigned short)(u >> 16);
}
__device__ inline unsigned int cvt_pk_bf16(float lo, float hi) {
  unsigned int r;
  asm("v_cvt_pk_bf16_f32 %0, %1, %2" : "=v"(r) : "v"(lo), "v"(hi));
  return r;
}
// tanh(x) = 1 - 2/(1+e^{2x}) = 1 - 2/(1+exp2(x*2log2e)); saturates for |x| large
__device__ inline float tanh_fast(float x) {
  float t = __builtin_amdgcn_exp2f(x * 2.885390082f);
  float r = __builtin_amdgcn_rcpf(t + 1.0f);
  return fmaf(-2.0f, r, 1.0f);
}

__global__ void maf_prep(const float* __restrict__ W1, const float* __restrict__ Wc,
                         const float* __restrict__ W2, unsigned short* __restrict__ ws) {
  int t = blockIdx.x * blockDim.x + threadIdx.x;     // 0 .. 163839
  if (t < 32768) {                                   // W1mT [h][d]
    int h = t >> 5, d = t & 31;
    int deg = h % 31 + 1;                            // hid_deg
    float v = (deg >= d + 1) ? W1[(size_t)d * HH + h] : 0.f;
    ws[t] = f2bf(v);
  } else if (t < 98304) {                            // W2mT [c][h]
    int i = t - 32768;
    int c = i >> 10, h = i & 1023;
    int deg = h % 31 + 1;
    float v = (((c >> 1) + 1) > deg) ? W2[(size_t)h * 64 + c] : 0.f;
    ws[t] = f2bf(v);
  } else {                                           // WcT [h][c]
    int i = t - 98304;
    int h = i >> 6, c = i & 63;
    ws[t] = f2bf(Wc[(size_t)c * HH + h]);
  }
}

__global__ __launch_bounds__(1024, 4) void maf_main(
    const float* __restrict__ x, const float* __restrict__ ctx,
    const float* __restrict__ b1, const float* __restrict__ b2,
    const unsigned short* __restrict__ ws, float* __restrict__ out)
{
  // LDS: 66048 + 2560 + 34816 = 103424 B -> 1 block/CU (4 waves/SIMD)
  __shared__ __align__(16) unsigned short hidb[32][1032];  // hid bf16 [s][h]
  __shared__ __align__(16) unsigned short ybf[32][40];     // y bf16 [s][d]
  __shared__ __align__(16) float Pp4[4][32][68];           // GEMM2 K-quarter partials

  const unsigned short* W1mT = ws;            // [1024][32]
  const unsigned short* W2mT = ws + 32768;    // [64][1024]
  const unsigned short* WcT  = ws + 98304;    // [1024][64]

  const int tid  = threadIdx.x;
  const int lane = tid & 63;
  const int w    = tid >> 6;        // wave 0..15
  const int l15  = lane & 15;
  const int lk   = lane >> 4;       // 0..3
  const int s0   = blockIdx.x * 32;

  // zero y
  if (tid < 640) reinterpret_cast<unsigned int*>(&ybf[0][0])[tid] = 0u;

  // ---- ctx B-fragments from global (f32 -> bf16 via cvt_pk) ----
  short8 cf[2][2];
#pragma unroll
  for (int sh = 0; sh < 2; ++sh)
#pragma unroll
    for (int kc = 0; kc < 2; ++kc) {
      const float* cp = ctx + (size_t)(s0 + sh * 16 + l15) * 64 + kc * 32 + lk * 8;
      f32x4 a = *reinterpret_cast<const f32x4*>(cp);
      f32x4 b = *reinterpret_cast<const f32x4*>(cp + 4);
      union { short8 s; unsigned int u[4]; } t;
      t.u[0] = cvt_pk_bf16(a[0], a[1]);
      t.u[1] = cvt_pk_bf16(a[2], a[3]);
      t.u[2] = cvt_pk_bf16(b[0], b[1]);
      t.u[3] = cvt_pk_bf16(b[2], b[3]);
      cf[sh][kc] = t.s;
    }

  // ---- WcH^T + b1 for this wave's 64 h-rows; unpacked f32 (32 regs) ----
  f32x4 wch[2][4];
#pragma unroll
  for (int j = 0; j < 4; ++j) {
    int h0 = w * 64 + j * 16;
    f32x4 binit = *reinterpret_cast<const f32x4*>(b1 + h0 + 4 * lk);
#pragma unroll
    for (int sh = 0; sh < 2; ++sh) {
      f32x4 acc = binit;
#pragma unroll
      for (int kc = 0; kc < 2; ++kc) {
        short8 af = *reinterpret_cast<const short8*>(WcT + (size_t)(h0 + l15) * 64 + kc * 32 + lk * 8);
        acc = __builtin_amdgcn_mfma_f32_16x16x32_bf16(af, cf[sh][kc], acc, 0, 0, 0);
      }
      wch[sh][j] = acc;
    }
  }

  // ---- W1 A-fragments, register-resident (16 regs) ----
  short8 w1f[4];
#pragma unroll
  for (int j = 0; j < 4; ++j)
    w1f[j] = *reinterpret_cast<const short8*>(W1mT + (size_t)(w * 64 + j * 16 + l15) * 32 + lk * 8);

  // ---- W2 B-fragments, register-resident (32 regs); wave = (ct, kq) ----
  const int ct = w & 3, kq = w >> 2;
  short8 w2f[8];
#pragma unroll
  for (int ks = 0; ks < 8; ++ks)
    w2f[ks] = *reinterpret_cast<const short8*>(
        W2mT + (size_t)(16 * ct + l15) * 1024 + kq * 256 + ks * 32 + lk * 8);

  // ---- epilogue role: thread -> (sample se, dim de) ----
  const int se = tid >> 5, de = tid & 31;
  const float xv  = x[(size_t)(s0 + se) * 32 + de];
  const float b2e = b2[2 * de], b2o = b2[2 * de + 1];
  float ls_last = 0.f;

  __syncthreads();

#pragma unroll 1
  for (int step = 0; step < 32; ++step) {
    // ---- GEMM1: hidT[h][s] = W1m^T @ y^T (+WcH); 4 h-subtiles per wave ----
    short8 yb0 = *reinterpret_cast<const short8*>(&ybf[l15][lk * 8]);
    short8 yb1 = *reinterpret_cast<const short8*>(&ybf[16 + l15][lk * 8]);
#pragma unroll
    for (int j = 0; j < 4; ++j) {
      f32x4 c0 = __builtin_amdgcn_mfma_f32_16x16x32_bf16(w1f[j], yb0, wch[0][j], 0, 0, 0);
      f32x4 c1 = __builtin_amdgcn_mfma_f32_16x16x32_bf16(w1f[j], yb1, wch[1][j], 0, 0, 0);
      int h0 = w * 64 + j * 16;
      uint2 q0, q1;
      q0.x = cvt_pk_bf16(tanh_fast(c0[0]), tanh_fast(c0[1]));
      q0.y = cvt_pk_bf16(tanh_fast(c0[2]), tanh_fast(c0[3]));
      q1.x = cvt_pk_bf16(tanh_fast(c1[0]), tanh_fast(c1[1]));
      q1.y = cvt_pk_bf16(tanh_fast(c1[2]), tanh_fast(c1[3]));
      *reinterpret_cast<uint2*>(&hidb[l15][h0 + 4 * lk]) = q0;       // sample l15
      *reinterpret_cast<uint2*>(&hidb[16 + l15][h0 + 4 * lk]) = q1;  // sample 16+l15
    }
    __syncthreads();

    // ---- GEMM2: P[s][c] partial over this wave's K-quarter; W2 from regs ----
    {
      const unsigned short* ha0 = &hidb[l15][kq * 256 + lk * 8];
      const unsigned short* ha1 = &hidb[16 + l15][kq * 256 + lk * 8];
      f32x4 p0 = {0.f, 0.f, 0.f, 0.f}, p1 = {0.f, 0.f, 0.f, 0.f};
#pragma unroll
      for (int ks = 0; ks < 8; ++ks) {
        short8 a0 = *reinterpret_cast<const short8*>(ha0 + ks * 32);
        p0 = __builtin_amdgcn_mfma_f32_16x16x32_bf16(a0, w2f[ks], p0, 0, 0, 0);
        short8 a1 = *reinterpret_cast<const short8*>(ha1 + ks * 32);
        p1 = __builtin_amdgcn_mfma_f32_16x16x32_bf16(a1, w2f[ks], p1, 0, 0, 0);
      }
#pragma unroll
      for (int r = 0; r < 4; ++r) {
        Pp4[kq][4 * lk + r][16 * ct + l15]      = p0[r];
        Pp4[kq][16 + 4 * lk + r][16 * ct + l15] = p1[r];
      }
    }
    __syncthreads();

    // ---- epilogue: thread (se, de): sum K-quarters, y = x*exp(ls) + sh ----
    {
      float sh = b2e, ls = b2o;
#pragma unroll
      for (int q = 0; q < 4; ++q) {
        float2 v = *reinterpret_cast<const float2*>(&Pp4[q][se][2 * de]);
        sh += v.x; ls += v.y;
      }
      float yv = fmaf(xv, __expf(ls), sh);
      ybf[se][de] = f2bf(yv);
      if (step == 31) {
        out[(size_t)(s0 + se) * 32 + de] = yv;
        ls_last = ls;
      }
    }
    __syncthreads();
  }

  // ---- log_det: reduce ls over de within each 32-lane group ----
  float v = ls_last;
  v += __shfl_xor(v, 1);
  v += __shfl_xor(v, 2);
  v += __shfl_xor(v, 4);
  v += __shfl_xor(v, 8);
  v += __shfl_xor(v, 16);
  if (de == 0) out[(size_t)NS * 32 + s0 + se] = v;
}

extern "C" void kernel_launch(void* const* d_in, const int* in_sizes, int n_in,
                              void* d_out, int out_size, void* d_ws, size_t ws_size,
                              hipStream_t stream) {
  (void)in_sizes; (void)n_in; (void)out_size; (void)ws_size;
  const float* x   = (const float*)d_in[0];
  const float* ctx = (const float*)d_in[1];
  const float* W1  = (const float*)d_in[2];
  const float* b1  = (const float*)d_in[3];
  const float* Wc  = (const float*)d_in[4];
  const float* W2  = (const float*)d_in[5];
  const float* b2  = (const float*)d_in[6];
  unsigned short* ws = (unsigned short*)d_ws;
  float* out = (float*)d_out;

  maf_prep<<<640, 256, 0, stream>>>(W1, Wc, W2, ws);
  maf_main<<<2048, 1024, 0, stream>>>(x, ctx, b1, b2, ws, out);
}